// Round 8
// baseline (585.113 us; speedup 1.0000x reference)
//
#include <hip/hip_runtime.h>

// NCC forward: X,Y (16,32,64,24) fp32, PS=5, D=2, EPS=0.01
// out[blk*184320 + (yo*24+i)*1536 + h*24 + x] =
//   (cross - Em(h,x)*SF(h+yo,i)) * IE(h,x) * IF(h+yo,i)
// cross = sum_{dy,dx} Xp[h+dy][x+dx] * Yp[h+yo+dy][i+dx]
//
// Grid: 1024 blocks = (channel, h-half). Block = 384 thr = 6 waves.
// Thread = (x2 = tid%12, hl = tid/12): owns 2 consecutive x at one h; sweeps i.
// float2 stores; wave writes 512B contiguous full-line chunks of each plane.
// Occupancy plan: VGPR<=102 via launch_bounds(384,5) -> 5 waves/SIMD ->
// 3 blocks/CU = 18 waves/CU (R5 level) with R6's per-output instruction diet.
// Y staged transposed [col][row-local] stride 41 (coprime w/ 32 banks); Y
// window yw[9][5] rolls along i with mod-5 compile-time slots (step_i<K>).

#define NT 384

template<int K>
__device__ __forceinline__ void step_i(
    int i, int hl,
    const float* __restrict__ sYT, const float* __restrict__ sFI,
    const float (&Xw)[5][6], float (&yw)[9][5],
    const float (&Em)[2], const float (&IE)[2],
    float* __restrict__ outT)
{
    // roll in Y column i+4 (local rows hl..hl+8) -> slot (K+4)%5
    const float* yc = &sYT[(i + 4) * 41 + hl];
    #pragma unroll
    for (int dr = 0; dr < 9; ++dr) yw[dr][(K + 4) % 5] = yc[dr];

    // cross for 2 x-positions x 5 yo: 250 FMA, all register operands
    float cr[2][5];
    #pragma unroll
    for (int q = 0; q < 2; ++q)
        #pragma unroll
        for (int yo = 0; yo < 5; ++yo) cr[q][yo] = 0.f;

    #pragma unroll
    for (int dy = 0; dy < 5; ++dy) {
        #pragma unroll
        for (int dx = 0; dx < 5; ++dx) {
            #pragma unroll
            for (int yo = 0; yo < 5; ++yo) {
                const float yv = yw[dy + yo][(K + dx) % 5];
                cr[0][yo] = fmaf(Xw[dy][dx],     yv, cr[0][yo]);
                cr[1][yo] = fmaf(Xw[dy][dx + 1], yv, cr[1][yo]);
            }
        }
    }

    // (SF, 1/Fs) local rows hl..hl+4 at col i; emit 5 float2 stores
    const float2* fi = (const float2*)&sFI[(i * 36 + hl) * 2];
    #pragma unroll
    for (int yo = 0; yo < 5; ++yo) {
        float2 f = fi[yo];
        float2 v;
        v.x = fmaf(-Em[0], f.x, cr[0][yo]) * (IE[0] * f.y);
        v.y = fmaf(-Em[1], f.x, cr[1][yo]) * (IE[1] * f.y);
        *(float2*)(outT + (size_t)(yo * 24 + i) * 1536) = v;
    }
}

__global__ __launch_bounds__(NT, 5)
void ncc_kernel(const float* __restrict__ X, const float* __restrict__ Y,
                float* __restrict__ out)
{
    __shared__ float sXp[36 * 28];        // Xp rows: local j = X row (r0-2+j)
    __shared__ float sYT[28 * 41];        // Yp transposed [col][local row j = Yp row r0+j]
    __shared__ float sFI[24 * 36 * 2];    // (SF, 1/Fs) per (i, local r)

    const int tid  = threadIdx.x;
    const int bid  = blockIdx.x;
    const int half = bid & 1;
    const int blk  = bid >> 1;            // = b*32 + c
    const int r0   = half * 32;

    const float* Xc = X + (size_t)blk * 1536;
    const float* Yc = Y + (size_t)blk * 1536;
    float* outC = out + (size_t)blk * 184320;

    // ---- Phase A: stage padded inputs (coalesced reads) ----
    for (int idx = tid; idx < 36 * 28; idx += NT) {
        int j = idx / 28, cc = idx - j * 28;
        int hh = r0 + j - 2, ww = cc - 2;          // X pad = 2
        float v = 0.f;
        if ((unsigned)hh < 64u && (unsigned)ww < 24u) v = Xc[hh * 24 + ww];
        sXp[idx] = v;
    }
    for (int idx = tid; idx < 40 * 28; idx += NT) {
        int j = idx / 28, cc = idx - j * 28;
        int hh = r0 + j - 4, ww = cc - 2;          // Y pad = 4 (H), 2 (W)
        float v = 0.f;
        if ((unsigned)hh < 64u && (unsigned)ww < 24u) v = Yc[hh * 24 + ww];
        sYT[cc * 41 + j] = v;                      // transposed write
    }
    __syncthreads();

    // ---- Phase B: Y patch statistics ----
    for (int idx = tid; idx < 24 * 36; idx += NT) {
        int ii = idx / 36, j = idx - ii * 36;
        float s = 0.f, s2 = 0.f;
        #pragma unroll
        for (int dx = 0; dx < 5; ++dx)
            #pragma unroll
            for (int dy = 0; dy < 5; ++dy) {
                float v = sYT[(ii + dx) * 41 + j + dy];
                s += v; s2 = fmaf(v, v, s2);
            }
        float var = fmaxf((s2 - s * s * 0.04f) * (1.f / 24.f), 0.f);
        float2 fv;
        fv.x = s;                                   // SF (patch sum)
        fv.y = 1.f / (sqrtf(var) + 0.01f);          // 1/Fs
        *(float2*)&sFI[(ii * 36 + j) * 2] = fv;
    }
    __syncthreads();

    // ---- Phase C setup: thread = (x2, hl) ----
    const int x2 = tid % 12;
    const int hl = tid / 12;               // 0..31
    const int xb = x2 * 2;

    float Xw[5][6];                        // X rows hl..hl+4 (local), cols xb..xb+5
    #pragma unroll
    for (int dy = 0; dy < 5; ++dy)
        #pragma unroll
        for (int c = 0; c < 6; ++c)
            Xw[dy][c] = sXp[(hl + dy) * 28 + xb + c];

    float Em[2], IE[2];
    {
        float colS[6], colQ[6];
        #pragma unroll
        for (int c = 0; c < 6; ++c) {
            float s = 0.f, s2 = 0.f;
            #pragma unroll
            for (int dy = 0; dy < 5; ++dy) {
                float v = Xw[dy][c];
                s += v; s2 = fmaf(v, v, s2);
            }
            colS[c] = s; colQ[c] = s2;
        }
        #pragma unroll
        for (int q = 0; q < 2; ++q) {
            float s  = colS[q] + colS[q+1] + colS[q+2] + colS[q+3] + colS[q+4];
            float s2 = colQ[q] + colQ[q+1] + colQ[q+2] + colQ[q+3] + colQ[q+4];
            float var = fmaxf((s2 - s * s * 0.04f) * (1.f / 24.f), 0.f);
            Em[q] = s * 0.04f;
            IE[q] = 1.f / (25.f * (sqrtf(var) + 0.01f));
        }
    }

    float yw[9][5];                        // Y local rows hl..hl+8, rolling cols
    #pragma unroll
    for (int c = 0; c < 4; ++c) {          // prefill cols 0..3 -> slots 0..3
        const float* yc = &sYT[c * 41 + hl];
        #pragma unroll
        for (int dr = 0; dr < 9; ++dr) yw[dr][c] = yc[dr];
    }

    float* outT = outC + (size_t)(r0 + hl) * 24 + xb;

    // ---- Phase C: 24 i-steps ----
    #pragma unroll 1
    for (int t5 = 0; t5 < 20; t5 += 5) {
        step_i<0>(t5 + 0, hl, sYT, sFI, Xw, yw, Em, IE, outT);
        step_i<1>(t5 + 1, hl, sYT, sFI, Xw, yw, Em, IE, outT);
        step_i<2>(t5 + 2, hl, sYT, sFI, Xw, yw, Em, IE, outT);
        step_i<3>(t5 + 3, hl, sYT, sFI, Xw, yw, Em, IE, outT);
        step_i<4>(t5 + 4, hl, sYT, sFI, Xw, yw, Em, IE, outT);
    }
    step_i<0>(20, hl, sYT, sFI, Xw, yw, Em, IE, outT);
    step_i<1>(21, hl, sYT, sFI, Xw, yw, Em, IE, outT);
    step_i<2>(22, hl, sYT, sFI, Xw, yw, Em, IE, outT);
    step_i<3>(23, hl, sYT, sFI, Xw, yw, Em, IE, outT);
}

extern "C" void kernel_launch(void* const* d_in, const int* in_sizes, int n_in,
                              void* d_out, int out_size, void* d_ws, size_t ws_size,
                              hipStream_t stream) {
    const float* X = (const float*)d_in[0];
    const float* Y = (const float*)d_in[1];
    float* out = (float*)d_out;
    ncc_kernel<<<dim3(16 * 32 * 2), dim3(NT), 0, stream>>>(X, Y, out);
}

// Round 9
// 167.140 us; speedup vs baseline: 3.5007x; 3.5007x over previous
//
#include <hip/hip_runtime.h>

// NCC forward: X,Y (16,32,64,24) fp32, PS=5, D=2, EPS=0.01
// out[blk*184320 + (yo*24+i)*1536 + p],  p = h*24+x, blk = b*32+c
//   = (cross - Em(h,x)*SF(h+yo,i)) * IE(h,x) * IF(h+yo,i)
// cross = sum_{dy,dx} Xp[h+dy][x+dx] * Yp[h+yo+dy][i+dx]
//
// Grid = 1536 blocks: (tile 0..2) x (channel 0..511); block = 256 thr = 4 waves
// (fine occupancy granularity: 4 blocks/CU = 16 waves at VGPR<=128).
// Thread owns 2 consecutive flat positions p = p0 + 2*tid (p even -> the x-pair
// never crosses a row); sweeps i 0..23. Wave store = 512B contiguous float2.
// X window Xw[5][6] in regs (loaded once); X stats in-register. Y window
// yw[9][5] rolls along i with mod-5 compile-time slots (step_i<K>). Y staged
// transposed [col][local row] stride 31; (SF,1/Fs) interleaved per (i, row).

#define NT 256

template<int K>
__device__ __forceinline__ void step_i(
    int i, int lh,
    const float* __restrict__ sYT, const float* __restrict__ sFI,
    const float (&Xw)[5][6], float (&yw)[9][5],
    const float (&Em)[2], const float (&IE)[2],
    float* __restrict__ outT)
{
    // roll in Yp column i+4 (local rows lh..lh+8) -> slot (K+4)%5
    const float* yc = &sYT[(i + 4) * 31 + lh];
    #pragma unroll
    for (int dr = 0; dr < 9; ++dr) yw[dr][(K + 4) % 5] = yc[dr];

    // cross for 2 x-positions x 5 yo: 250 FMA, all register operands
    float cr[2][5];
    #pragma unroll
    for (int q = 0; q < 2; ++q)
        #pragma unroll
        for (int yo = 0; yo < 5; ++yo) cr[q][yo] = 0.f;

    #pragma unroll
    for (int dy = 0; dy < 5; ++dy) {
        #pragma unroll
        for (int dx = 0; dx < 5; ++dx) {
            #pragma unroll
            for (int yo = 0; yo < 5; ++yo) {
                const float yv = yw[dy + yo][(K + dx) % 5];
                cr[0][yo] = fmaf(Xw[dy][dx],     yv, cr[0][yo]);
                cr[1][yo] = fmaf(Xw[dy][dx + 1], yv, cr[1][yo]);
            }
        }
    }

    // (SF, 1/Fs) stat rows lh..lh+4 at col i; emit 5 float2 stores (512B/wave)
    const float2* fi = (const float2*)&sFI[(i * 26 + lh) * 2];
    #pragma unroll
    for (int yo = 0; yo < 5; ++yo) {
        float2 f = fi[yo];
        float2 v;
        v.x = fmaf(-Em[0], f.x, cr[0][yo]) * (IE[0] * f.y);
        v.y = fmaf(-Em[1], f.x, cr[1][yo]) * (IE[1] * f.y);
        *(float2*)(outT + (size_t)(yo * 24 + i) * 1536) = v;
    }
}

__global__ __launch_bounds__(NT, 4)
void ncc_kernel(const float* __restrict__ X, const float* __restrict__ Y,
                float* __restrict__ out)
{
    __shared__ float sXp[26 * 28];        // X rows hx0-2 .. hx0+23, padded cols
    __shared__ float sYT[28 * 31];        // Y transposed [col][j], j = Yrow-(hx0-4), 30 rows
    __shared__ float sFI[24 * 26 * 2];    // (SF, 1/Fs) per (i, js), stat row = hx0+js

    const int tid  = threadIdx.x;
    const int bid  = blockIdx.x;
    const int tile = bid >> 9;            // 0..2
    const int blk  = bid & 511;           // = b*32 + c
    const int p0   = tile * 512;
    const int hx0  = (tile == 0) ? 0 : (tile == 1 ? 21 : 42);   // p0/24

    const float* Xc = X + (size_t)blk * 1536;
    const float* Yc = Y + (size_t)blk * 1536;
    float* outC = out + (size_t)blk * 184320;

    // ---- Phase A: stage padded sub-tiles ----
    for (int idx = tid; idx < 26 * 28; idx += NT) {
        int j = idx / 28, cc = idx - j * 28;
        int hh = hx0 + j - 2, ww = cc - 2;          // X pad = 2 (H and W)
        float v = 0.f;
        if ((unsigned)hh < 64u && (unsigned)ww < 24u) v = Xc[hh * 24 + ww];
        sXp[idx] = v;
    }
    for (int idx = tid; idx < 30 * 28; idx += NT) {
        int j = idx / 28, cc = idx - j * 28;
        int hh = hx0 + j - 4, ww = cc - 2;          // Y pad = 4 (H), 2 (W)
        float v = 0.f;
        if ((unsigned)hh < 64u && (unsigned)ww < 24u) v = Yc[hh * 24 + ww];
        sYT[cc * 31 + j] = v;                       // transposed write
    }
    __syncthreads();

    // ---- Phase B: Y patch statistics (stat row s = hx0+js, Yp coords) ----
    for (int idx = tid; idx < 24 * 26; idx += NT) {
        int ii = idx / 26, js = idx - ii * 26;
        float s = 0.f, s2 = 0.f;
        #pragma unroll
        for (int dx = 0; dx < 5; ++dx)
            #pragma unroll
            for (int dy = 0; dy < 5; ++dy) {
                float v = sYT[(ii + dx) * 31 + js + dy];
                s += v; s2 = fmaf(v, v, s2);
            }
        float var = fmaxf((s2 - s * s * 0.04f) * (1.f / 24.f), 0.f);
        float2 fv;
        fv.x = s;                                    // SF (patch sum)
        fv.y = 1.f / (sqrtf(var) + 0.01f);           // 1/Fs
        *(float2*)&sFI[(ii * 26 + js) * 2] = fv;
    }
    __syncthreads();

    // ---- Phase C setup: thread owns flat positions pt, pt+1 ----
    const int pt = p0 + 2 * tid;          // even -> x even, pair stays in-row
    const int h  = pt / 24;
    const int x  = pt - h * 24;           // 0..22 even
    const int lh = h - hx0;               // 0..21

    float Xw[5][6];                        // Xp rows h..h+4, cols x..x+5
    #pragma unroll
    for (int dy = 0; dy < 5; ++dy)
        #pragma unroll
        for (int c = 0; c < 6; ++c)
            Xw[dy][c] = sXp[(lh + dy) * 28 + x + c];

    float Em[2], IE[2];                    // in-register X patch stats
    {
        float colS[6], colQ[6];
        #pragma unroll
        for (int c = 0; c < 6; ++c) {
            float s = 0.f, s2 = 0.f;
            #pragma unroll
            for (int dy = 0; dy < 5; ++dy) {
                float v = Xw[dy][c];
                s += v; s2 = fmaf(v, v, s2);
            }
            colS[c] = s; colQ[c] = s2;
        }
        #pragma unroll
        for (int q = 0; q < 2; ++q) {
            float s  = colS[q] + colS[q+1] + colS[q+2] + colS[q+3] + colS[q+4];
            float s2 = colQ[q] + colQ[q+1] + colQ[q+2] + colQ[q+3] + colQ[q+4];
            float var = fmaxf((s2 - s * s * 0.04f) * (1.f / 24.f), 0.f);
            Em[q] = s * 0.04f;
            IE[q] = 1.f / (25.f * (sqrtf(var) + 0.01f));
        }
    }

    float yw[9][5];                        // Yp rows h..h+8, rolling cols
    #pragma unroll
    for (int c = 0; c < 4; ++c) {          // prefill Yp cols 0..3 -> slots 0..3
        const float* yc = &sYT[c * 31 + lh];
        #pragma unroll
        for (int dr = 0; dr < 9; ++dr) yw[dr][c] = yc[dr];
    }

    float* outT = outC + pt;

    // ---- Phase C: 24 i-steps (mod-5 compile-time slots) ----
    #pragma unroll 1
    for (int t5 = 0; t5 < 20; t5 += 5) {
        step_i<0>(t5 + 0, lh, sYT, sFI, Xw, yw, Em, IE, outT);
        step_i<1>(t5 + 1, lh, sYT, sFI, Xw, yw, Em, IE, outT);
        step_i<2>(t5 + 2, lh, sYT, sFI, Xw, yw, Em, IE, outT);
        step_i<3>(t5 + 3, lh, sYT, sFI, Xw, yw, Em, IE, outT);
        step_i<4>(t5 + 4, lh, sYT, sFI, Xw, yw, Em, IE, outT);
    }
    step_i<0>(20, lh, sYT, sFI, Xw, yw, Em, IE, outT);
    step_i<1>(21, lh, sYT, sFI, Xw, yw, Em, IE, outT);
    step_i<2>(22, lh, sYT, sFI, Xw, yw, Em, IE, outT);
    step_i<3>(23, lh, sYT, sFI, Xw, yw, Em, IE, outT);
}

extern "C" void kernel_launch(void* const* d_in, const int* in_sizes, int n_in,
                              void* d_out, int out_size, void* d_ws, size_t ws_size,
                              hipStream_t stream) {
    const float* X = (const float*)d_in[0];
    const float* Y = (const float*)d_in[1];
    float* out = (float*)d_out;
    ncc_kernel<<<dim3(3 * 512), dim3(NT), 0, stream>>>(X, Y, out);
}

// Round 10
// 104.648 us; speedup vs baseline: 5.5913x; 1.5972x over previous
//
#include <hip/hip_runtime.h>

// NCC forward: X,Y (16,32,64,24) fp32, PS=5, D=2, EPS=0.01
// out[blk*184320 + (yo*24+i)*1536 + h*24 + x] =
//   (cross - Em(h,x)*SF(h+yo,i)) * IE(h,x) * IF(h+yo,i)
// cross = sum_{dy,dx} Xp[h+dy][x+dx] * Yp[h+yo+dy][i+dx]
//
// R5 structure verbatim (512 blocks x 576 thr = 9 waves; thread=(x,h); 3
// h-tiles; sweep i with mod-5 compile-time col slots; scalar 256B/wave
// stores; launch_bounds(576,5) -> VGPR<=102 -> 2 blocks/CU = 18 waves/CU).
// R9 change: per-step LDS instrs 14 -> 8 via PARITY-SHIFTED DUPLICATE
// copies of Y (column-major, stride 74) and of the (SF,1/Fs) stat table:
// a thread at odd h reads the one-row-shifted copy, so both parities get
// aligned vector reads: roll = 5x ds_read_b64, stats = 3x ds_read_b128.
// Base pointer selected once at setup (no per-step cost).

#define NT 576

template<int K>
__device__ __forceinline__ void step_i(
    int i,
    const float2* __restrict__ pbY, const float4* __restrict__ pbF,
    const float (&Xw)[5][5], float (&yw)[9][5],
    float Em, float IE, float* __restrict__ outT)
{
    // roll in Yp column i+4, rows h..h+8: 5x b64 (10th float unused)
    const float2* q = pbY + (i + 4) * 37;
    float2 t0 = q[0], t1 = q[1], t2 = q[2], t3 = q[3], t4 = q[4];
    constexpr int s4 = (K + 4) % 5;
    yw[0][s4] = t0.x; yw[1][s4] = t0.y;
    yw[2][s4] = t1.x; yw[3][s4] = t1.y;
    yw[4][s4] = t2.x; yw[5][s4] = t2.y;
    yw[6][s4] = t3.x; yw[7][s4] = t3.y;
    yw[8][s4] = t4.x;

    // cross for 5 yo: 125 FMA, all register operands
    float cr[5] = {0.f, 0.f, 0.f, 0.f, 0.f};
    #pragma unroll
    for (int dy = 0; dy < 5; ++dy) {
        #pragma unroll
        for (int dx = 0; dx < 5; ++dx) {
            const float xv = Xw[dy][dx];
            #pragma unroll
            for (int yo = 0; yo < 5; ++yo)
                cr[yo] = fmaf(xv, yw[dy + yo][(K + dx) % 5], cr[yo]);
        }
    }

    // (SF,1/Fs) rows h..h+4 at col i: 3x b128 (6th row unused)
    const float4* fq = pbF + i * 34;
    float4 f0 = fq[0], f1 = fq[1], f2 = fq[2];
    const float sf[5] = {f0.x, f0.z, f1.x, f1.z, f2.x};
    const float iv[5] = {f0.y, f0.w, f1.y, f1.w, f2.y};
    #pragma unroll
    for (int yo = 0; yo < 5; ++yo) {
        float v = fmaf(-Em, sf[yo], cr[yo]) * (IE * iv[yo]);
        outT[(size_t)(yo * 24 + i) * 1536] = v;
    }
}

__global__ __launch_bounds__(NT, 5)
void ncc_kernel(const float* __restrict__ X, const float* __restrict__ Y,
                float* __restrict__ out)
{
    __shared__ __align__(16) float sXp[68 * 28];   // Xp row-major, rows 0..67
    __shared__ __align__(16) float sYe[28 * 74];   // Yp col-major [c][r], stride 74
    __shared__ __align__(16) float sYo[28 * 74];   // same, shifted: [c*74 + r-1] = Yp[c][r]
    __shared__ __align__(16) float sMI[64 * 24 * 2]; // (Em, IE) per (h,x)
    __shared__ __align__(16) float sFe[24 * 136];  // (SF,IF) interleaved [i][r], stride 136
    __shared__ __align__(16) float sFo[24 * 136];  // shifted copy: [i*136+(r-1)*2] = row r

    const int tid = threadIdx.x;
    const int blk = blockIdx.x;            // = b*32 + c
    const float* Xc = X + (size_t)blk * 1536;
    const float* Yc = Y + (size_t)blk * 1536;
    float* outC = out + (size_t)blk * 184320;

    // ---- Phase A: stage padded inputs (Y into both parity copies) ----
    for (int idx = tid; idx < 68 * 28; idx += NT) {
        int r = idx / 28, cc = idx - r * 28;
        int hh = r - 2, ww = cc - 2;
        float v = 0.f;
        if ((unsigned)hh < 64u && (unsigned)ww < 24u) v = Xc[hh * 24 + ww];
        sXp[idx] = v;
    }
    for (int idx = tid; idx < 72 * 28; idx += NT) {
        int r = idx / 28, cc = idx - r * 28;
        int hh = r - 4, ww = cc - 2;
        float v = 0.f;
        if ((unsigned)hh < 64u && (unsigned)ww < 24u) v = Yc[hh * 24 + ww];
        sYe[cc * 74 + r] = v;
        if (r > 0) sYo[cc * 74 + r - 1] = v;
    }
    __syncthreads();

    // ---- Phase B: patch statistics ----
    for (int idx = tid; idx < 64 * 24; idx += NT) {          // X stats -> sMI
        int hl = idx / 24, xx = idx - hl * 24;
        float s = 0.f, s2 = 0.f;
        #pragma unroll
        for (int dy = 0; dy < 5; ++dy)
            #pragma unroll
            for (int dx = 0; dx < 5; ++dx) {
                float v = sXp[(hl + dy) * 28 + xx + dx];
                s += v; s2 = fmaf(v, v, s2);
            }
        float var = fmaxf((s2 - s * s * 0.04f) * (1.f / 24.f), 0.f);
        sMI[idx * 2]     = s * 0.04f;                        // Em
        sMI[idx * 2 + 1] = 1.f / (25.f * (sqrtf(var) + 0.01f)); // 1/(25*Es)
    }
    for (int idx = tid; idx < 24 * 68; idx += NT) {          // Y stats -> sFe/sFo
        int ii = idx / 68, r = idx - ii * 68;
        float s = 0.f, s2 = 0.f;
        #pragma unroll
        for (int dx = 0; dx < 5; ++dx)
            #pragma unroll
            for (int dy = 0; dy < 5; ++dy) {
                float v = sYe[(ii + dx) * 74 + r + dy];
                s += v; s2 = fmaf(v, v, s2);
            }
        float var = fmaxf((s2 - s * s * 0.04f) * (1.f / 24.f), 0.f);
        float invf = 1.f / (sqrtf(var) + 0.01f);
        int be = ii * 136 + r * 2;
        sFe[be] = s; sFe[be + 1] = invf;
        if (r > 0) { int bo = ii * 136 + (r - 1) * 2; sFo[bo] = s; sFo[bo + 1] = invf; }
    }
    __syncthreads();

    // ---- Phase C: 3 h-tiles x 24 i-steps; thread = (x, h) ----
    const int x  = tid % 24;
    const int hl = tid / 24;

    #pragma unroll 1
    for (int ht = 0; ht < 3; ++ht) {
        const int h = ht * 24 + hl;
        if (h >= 64) break;               // wave-aligned (tid>=384 in tile 2)
        const int lo = h * 24 + x;

        float2 mi = *(const float2*)&sMI[lo * 2];
        const float Em = mi.x, IE = mi.y;

        // parity-selected aligned base pointers (setup-only cost)
        const float2* pbY = (h & 1) ? (const float2*)sYo + ((h - 1) >> 1)
                                    : (const float2*)sYe + (h >> 1);
        const float4* pbF = (h & 1) ? (const float4*)sFo + ((h - 1) >> 1)
                                    : (const float4*)sFe + (h >> 1);

        float Xw[5][5];                   // X window, loaded once per tile
        #pragma unroll
        for (int dy = 0; dy < 5; ++dy)
            #pragma unroll
            for (int dx = 0; dx < 5; ++dx)
                Xw[dy][dx] = sXp[(h + dy) * 28 + x + dx];

        float yw[9][5];                   // Yp rows h..h+8, rolling col slots
        #pragma unroll
        for (int c = 0; c < 4; ++c) {     // prefill cols 0..3 -> slots 0..3
            const float2* q = pbY + c * 37;
            float2 t0 = q[0], t1 = q[1], t2 = q[2], t3 = q[3], t4 = q[4];
            yw[0][c] = t0.x; yw[1][c] = t0.y;
            yw[2][c] = t1.x; yw[3][c] = t1.y;
            yw[4][c] = t2.x; yw[5][c] = t2.y;
            yw[6][c] = t3.x; yw[7][c] = t3.y;
            yw[8][c] = t4.x;
        }

        float* outT = outC + lo;

        #pragma unroll 1
        for (int t5 = 0; t5 < 20; t5 += 5) {
            step_i<0>(t5 + 0, pbY, pbF, Xw, yw, Em, IE, outT);
            step_i<1>(t5 + 1, pbY, pbF, Xw, yw, Em, IE, outT);
            step_i<2>(t5 + 2, pbY, pbF, Xw, yw, Em, IE, outT);
            step_i<3>(t5 + 3, pbY, pbF, Xw, yw, Em, IE, outT);
            step_i<4>(t5 + 4, pbY, pbF, Xw, yw, Em, IE, outT);
        }
        step_i<0>(20, pbY, pbF, Xw, yw, Em, IE, outT);
        step_i<1>(21, pbY, pbF, Xw, yw, Em, IE, outT);
        step_i<2>(22, pbY, pbF, Xw, yw, Em, IE, outT);
        step_i<3>(23, pbY, pbF, Xw, yw, Em, IE, outT);
    }
}

extern "C" void kernel_launch(void* const* d_in, const int* in_sizes, int n_in,
                              void* d_out, int out_size, void* d_ws, size_t ws_size,
                              hipStream_t stream) {
    const float* X = (const float*)d_in[0];
    const float* Y = (const float*)d_in[1];
    float* out = (float*)d_out;
    ncc_kernel<<<dim3(16 * 32), dim3(NT), 0, stream>>>(X, Y, out);
}